// Round 4
// baseline (569.363 us; speedup 1.0000x reference)
//
#include <hip/hip_runtime.h>

// MultiHeadGraphAttention: n=4096, n_head=8, f_in=1024, f_out=128
// score = s_i + d_j (rank-1); exp(leakyrelu(x)) separable:
//   x>=0: e^s * e^d  (test e^s*e^d >= 1),  x<0: e^{.2s} * e^{.2d}
// softmax normalization commutes with P@V -> accumulate unnormalized, scale in epilogue.
// Dtype self-detection per kernel (float inputs are fp32 on this harness; bf16 also handled).

#define N 4096
#define NH 8
#define FIN 1024
#define FOUT 128
#define LSTR 40

typedef short bf16x8 __attribute__((ext_vector_type(8)));
typedef float f32x4 __attribute__((ext_vector_type(4)));
typedef unsigned int uint;
typedef unsigned short ushort;

__device__ __forceinline__ float b2f(ushort u){ return __uint_as_float(((uint)u)<<16); }
__device__ __forceinline__ ushort f2b(float f){ uint u=__float_as_uint(f); u=(u+0x7fffu+((u>>16)&1u))>>16; return (ushort)u; }
__device__ __forceinline__ uint pk2(float a, float b){
    return (uint)f2b(a) | ((uint)f2b(b) << 16);
}
__device__ __forceinline__ float sane(float x, float lim){ return fminf(fmaxf(x,-lim),lim); }
// mode 0 = float tensors are bf16; mode 1 = fp32. Reads even ushorts of h:
// bf16 N(0,1) values have exponent in [90,141] ~always; fp32 low mantissa words ~20%.
__device__ __forceinline__ int detect_mode(const ushort* hraw){
    ushort u = hraw[2*(threadIdx.x & 63)];
    int e = (u>>7)&0xFF;
    unsigned long long m = __ballot(e>=90 && e<=141);
    return (__popcll(m)>=40)?0:1;
}

// -------------------------------------------------- pack adj into transposed bitmask
__global__ __launch_bounds__(256) void pack_adj(const int* __restrict__ adj,
                                                uint* __restrict__ bitsT) {
    size_t idx = (size_t)blockIdx.x * 256 + threadIdx.x;
    int v = adj[idx];
    unsigned long long m = __ballot(v != 0);
    int lane = threadIdx.x & 63;
    uint i  = (uint)(idx >> 12);
    uint jw = ((uint)idx & 4095u) >> 5;
    if (lane == 0)       bitsT[jw * N + i] = (uint)m;
    else if (lane == 32) bitsT[jw * N + i] = (uint)(m >> 32);
}

// -------------------------------------------------- w -> wT[h][o][f] (bf16)
__global__ __launch_bounds__(256) void transpose_w(const void* __restrict__ wraw,
                                                   const ushort* __restrict__ hraw,
                                                   ushort* __restrict__ wT) {
    __shared__ ushort tile[64][72];
    int mode = detect_mode(hraw);
    int h = blockIdx.z, f0 = blockIdx.x * 64, o0 = blockIdx.y * 64;
    int t = threadIdx.x;
#pragma unroll
    for (int it = 0; it < 2; ++it) {
        int slot = it * 256 + t;
        int row = slot >> 3, c = slot & 7;
        size_t eoff = (size_t)h * (FIN * FOUT) + (size_t)(f0 + row) * FOUT + o0 + c * 8;
        alignas(16) ushort tmp[8];
        if (mode == 0) {
            *reinterpret_cast<uint4*>(tmp) = *reinterpret_cast<const uint4*>((const ushort*)wraw + eoff);
        } else {
            const float* wF = (const float*)wraw;
            float4 x = *reinterpret_cast<const float4*>(wF + eoff);
            float4 y = *reinterpret_cast<const float4*>(wF + eoff + 4);
            tmp[0]=f2b(x.x); tmp[1]=f2b(x.y); tmp[2]=f2b(x.z); tmp[3]=f2b(x.w);
            tmp[4]=f2b(y.x); tmp[5]=f2b(y.y); tmp[6]=f2b(y.z); tmp[7]=f2b(y.w);
        }
        *reinterpret_cast<uint4*>(&tile[row][c * 8]) = *reinterpret_cast<uint4*>(tmp);
    }
    __syncthreads();
#pragma unroll
    for (int it = 0; it < 2; ++it) {
        int slot = it * 256 + t;
        int orow = slot >> 3, c = slot & 7;
        alignas(16) ushort tmp[8];
#pragma unroll
        for (int k = 0; k < 8; ++k) tmp[k] = tile[c * 8 + k][orow];
        *reinterpret_cast<uint4*>(wT + (size_t)h * (FIN * FOUT) + (size_t)(o0 + orow) * FIN + f0 + c * 8) =
            *reinterpret_cast<uint4*>(tmp);
    }
}

// -------------------------------------------------- zero acc32 (4M floats) + lsum (32k floats)
__global__ __launch_bounds__(256) void zero2(float* __restrict__ acc, float* __restrict__ lsum) {
    int b = blockIdx.x, t = threadIdx.x;
    float4 z; z.x=0.f; z.y=0.f; z.z=0.f; z.w=0.f;
    if (b < 4096) reinterpret_cast<float4*>(acc)[b*256+t] = z;
    else          reinterpret_cast<float4*>(lsum)[(b-4096)*256+t] = z;
}

// -------------------------------------------------- GEMM h' + fused s/d dots + exp tables
__global__ __launch_bounds__(256) void gemm_hp(
        const void* __restrict__ hraw, const ushort* __restrict__ wT,
        const void* __restrict__ asraw, const void* __restrict__ adraw,
        ushort* __restrict__ hpT,
        float* __restrict__ es1, float* __restrict__ es2,
        float* __restrict__ ed1, float* __restrict__ ed2) {
    __shared__ ushort As[128 * LSTR];
    __shared__ ushort Bs[128 * LSTR];
    __shared__ float sred[2][128];
    __shared__ float dred[2][128];
    int mode = detect_mode((const ushort*)hraw);
    int tid = threadIdx.x;
    int head = blockIdx.x;
    int i0 = blockIdx.y * 128;
    const ushort* hU = (const ushort*)hraw;
    const float*  hF = (const float*)hraw;
    const ushort* Bg = wT + (size_t)head * (FIN * FOUT);
    int wave = tid >> 6, lane = tid & 63;
    int wm = wave >> 1, wn = wave & 1, quad = lane >> 4, l16 = lane & 15;

    float asv[4], adv[4];
#pragma unroll
    for (int n = 0; n < 4; ++n) {
        int ai = head * FOUT + wn * 64 + n * 16 + l16;
        asv[n] = mode ? ((const float*)asraw)[ai] : b2f(((const ushort*)asraw)[ai]);
        adv[n] = mode ? ((const float*)adraw)[ai] : b2f(((const ushort*)adraw)[ai]);
    }

    f32x4 acc[4][4] = {};
    for (int k0 = 0; k0 < FIN; k0 += 32) {
        __syncthreads();
#pragma unroll
        for (int it = 0; it < 2; ++it) {
            int slot = it * 256 + tid;
            int row = slot >> 2, c = slot & 3;
            size_t aoff = (size_t)(i0 + row) * FIN + k0 + c * 8;
            uint4 av;
            if (mode == 0) {
                av = *reinterpret_cast<const uint4*>(hU + aoff);
            } else {
                float4 x = *reinterpret_cast<const float4*>(hF + aoff);
                float4 y = *reinterpret_cast<const float4*>(hF + aoff + 4);
                av.x = pk2(x.x, x.y); av.y = pk2(x.z, x.w);
                av.z = pk2(y.x, y.y); av.w = pk2(y.z, y.w);
            }
            *reinterpret_cast<uint4*>(&As[row * LSTR + c * 8]) = av;
            *reinterpret_cast<uint4*>(&Bs[row * LSTR + c * 8]) =
                *reinterpret_cast<const uint4*>(Bg + (size_t)row * FIN + k0 + c * 8);
        }
        __syncthreads();
        bf16x8 a[4], b[4];
#pragma unroll
        for (int m = 0; m < 4; ++m)
            a[m] = *reinterpret_cast<const bf16x8*>(&As[(wm * 64 + m * 16 + l16) * LSTR + quad * 8]);
#pragma unroll
        for (int n = 0; n < 4; ++n)
            b[n] = *reinterpret_cast<const bf16x8*>(&Bs[(wn * 64 + n * 16 + l16) * LSTR + quad * 8]);
#pragma unroll
        for (int m = 0; m < 4; ++m)
#pragma unroll
            for (int n = 0; n < 4; ++n)
                acc[m][n] = __builtin_amdgcn_mfma_f32_16x16x32_bf16(a[m], b[n], acc[m][n], 0, 0, 0);
    }
    // store hpT[h][o][i]
#pragma unroll
    for (int m = 0; m < 4; ++m) {
#pragma unroll
        for (int n = 0; n < 4; ++n) {
            int col = wn * 64 + n * 16 + l16;
            int rbase = i0 + wm * 64 + m * 16 + quad * 4;
            ushort4 pk;
            pk.x = f2b(acc[m][n][0]); pk.y = f2b(acc[m][n][1]);
            pk.z = f2b(acc[m][n][2]); pk.w = f2b(acc[m][n][3]);
            *reinterpret_cast<ushort4*>(hpT + (size_t)head * (FOUT * N) + (size_t)col * N + rbase) = pk;
        }
    }
    // fused s,d dot reduction (over o) + exp tables
#pragma unroll
    for (int m = 0; m < 4; ++m) {
#pragma unroll
        for (int r = 0; r < 4; ++r) {
            float s = 0.f, d = 0.f;
#pragma unroll
            for (int n = 0; n < 4; ++n) { s += acc[m][n][r] * asv[n]; d += acc[m][n][r] * adv[n]; }
#pragma unroll
            for (int off = 1; off < 16; off <<= 1) { s += __shfl_xor(s, off); d += __shfl_xor(d, off); }
            if (l16 == 0) {
                int row = wm * 64 + m * 16 + quad * 4 + r;
                sred[wn][row] = s; dred[wn][row] = d;
            }
        }
    }
    __syncthreads();
    if (tid < 128) {
        int i = i0 + tid;
        float s = sane(sred[0][tid] + sred[1][tid], 30.f);
        float d = sane(dred[0][tid] + dred[1][tid], 30.f);
        es1[head * N + i] = __expf(s);       es2[head * N + i] = __expf(0.2f * s);
        ed1[head * N + i] = __expf(d);       ed2[head * N + i] = __expf(0.2f * d);
    }
}

// -------------------------------------------------- l row-sums (j-split, atomic)
__global__ __launch_bounds__(256) void rowsum(const float* __restrict__ es1, const float* __restrict__ es2,
                                              const float* __restrict__ ed1, const float* __restrict__ ed2,
                                              const uint* __restrict__ bitsT, float* __restrict__ lsum) {
    int hh = blockIdx.z;
    int i = blockIdx.x * 256 + threadIdx.x;
    int w0 = blockIdx.y * 32;
    float e1i = es1[hh * N + i], e2i = es2[hh * N + i];
    const float* p1 = ed1 + hh * N + w0 * 32;
    const float* p2 = ed2 + hh * N + w0 * 32;
    float acc = 0.f;
    for (int w = 0; w < 32; ++w) {
        uint word = bitsT[(size_t)(w0 + w) * N + i];
#pragma unroll
        for (int b = 0; b < 32; ++b) {
            float t1 = e1i * p1[w * 32 + b];
            float e = (t1 >= 1.0f) ? t1 : e2i * p2[w * 32 + b];
            acc += ((word >> b) & 1u) ? e : 0.f;
        }
    }
    atomicAdd(&lsum[hh * N + i], acc);
}

__global__ __launch_bounds__(256) void recip(const float* __restrict__ lsum,
                                             float* __restrict__ rinv) {
    int idx = blockIdx.x * 256 + threadIdx.x;
    float v = lsum[idx];
    rinv[idx] = (v > 1e-30f) ? 1.0f / v : 0.f;
}

// -------------------------------------------------- pv: unnormalized P @ h', barrier-free
// Wave tile 64i x 64o; A-frags built in registers in MFMA layout; B-frags 16B lane loads.
// K-split x4, atomic fp32 accumulate.
__global__ __launch_bounds__(256, 4) void pv_kernel(
        const ushort* __restrict__ hpT,
        const float* __restrict__ es1, const float* __restrict__ es2,
        const float* __restrict__ ed1, const float* __restrict__ ed2,
        const uint* __restrict__ bitsT,
        float* __restrict__ acc32) {
    int t = threadIdx.x;
    int i0 = blockIdx.x * 128, hh = blockIdx.y, kb = blockIdx.z * 1024;
    int wave = t >> 6, lane = t & 63;
    int wm = wave >> 1, wn = wave & 1, quad = lane >> 4, l16 = lane & 15;
    int wsh = quad * 8;
    float s1[4], s2[4];
#pragma unroll
    for (int mi = 0; mi < 4; ++mi) {
        int i = i0 + wm * 64 + mi * 16 + l16;
        s1[mi] = es1[hh * N + i];
        s2[mi] = es2[hh * N + i];
    }
    const ushort* bp[4];
#pragma unroll
    for (int n = 0; n < 4; ++n)
        bp[n] = hpT + ((size_t)hh * FOUT + wn * 64 + n * 16 + l16) * N + wsh;
    const float* e1p = ed1 + hh * N + wsh;
    const float* e2p = ed2 + hh * N + wsh;
    const uint* wp = bitsT + (size_t)(kb >> 5) * N + i0 + wm * 64 + l16;
    f32x4 acc[4][4] = {};

    for (int k0 = kb; k0 < kb + 1024; k0 += 32) {
        bf16x8 b[4];
#pragma unroll
        for (int n = 0; n < 4; ++n)
            b[n] = *reinterpret_cast<const bf16x8*>(bp[n] + k0);
        float4 d1a = *reinterpret_cast<const float4*>(e1p + k0);
        float4 d1b = *reinterpret_cast<const float4*>(e1p + k0 + 4);
        float4 d2a = *reinterpret_cast<const float4*>(e2p + k0);
        float4 d2b = *reinterpret_cast<const float4*>(e2p + k0 + 4);
        const uint* wrow = wp + (size_t)((k0 - kb) >> 5) * N;
#pragma unroll
        for (int mi = 0; mi < 4; ++mi) {
            uint w = wrow[mi * 16] >> wsh;
            float p, q, e0, e1, e2, e3, e4, e5, e6, e7;
            p = s1[mi]*d1a.x; q = s2[mi]*d2a.x; e0 = (p>=1.f)?p:q; e0 = (w&1u)   ? e0 : 0.f;
            p = s1[mi]*d1a.y; q = s2[mi]*d2a.y; e1 = (p>=1.f)?p:q; e1 = (w&2u)   ? e1 : 0.f;
            p = s1[mi]*d1a.z; q = s2[mi]*d2a.z; e2 = (p>=1.f)?p:q; e2 = (w&4u)   ? e2 : 0.f;
            p = s1[mi]*d1a.w; q = s2[mi]*d2a.w; e3 = (p>=1.f)?p:q; e3 = (w&8u)   ? e3 : 0.f;
            p = s1[mi]*d1b.x; q = s2[mi]*d2b.x; e4 = (p>=1.f)?p:q; e4 = (w&16u)  ? e4 : 0.f;
            p = s1[mi]*d1b.y; q = s2[mi]*d2b.y; e5 = (p>=1.f)?p:q; e5 = (w&32u)  ? e5 : 0.f;
            p = s1[mi]*d1b.z; q = s2[mi]*d2b.z; e6 = (p>=1.f)?p:q; e6 = (w&64u)  ? e6 : 0.f;
            p = s1[mi]*d1b.w; q = s2[mi]*d2b.w; e7 = (p>=1.f)?p:q; e7 = (w&128u) ? e7 : 0.f;
            uint4 av; av.x = pk2(e0, e1); av.y = pk2(e2, e3); av.z = pk2(e4, e5); av.w = pk2(e6, e7);
            bf16x8 a = *reinterpret_cast<bf16x8*>(&av);
#pragma unroll
            for (int n = 0; n < 4; ++n)
                acc[mi][n] = __builtin_amdgcn_mfma_f32_16x16x32_bf16(a, b[n], acc[mi][n], 0, 0, 0);
        }
    }
#pragma unroll
    for (int mi = 0; mi < 4; ++mi) {
#pragma unroll
        for (int n = 0; n < 4; ++n) {
            int col = wn * 64 + n * 16 + l16;
#pragma unroll
            for (int r = 0; r < 4; ++r) {
                int i = i0 + wm * 64 + mi * 16 + quad * 4 + r;
                atomicAdd(&acc32[((size_t)hh * N + i) * FOUT + col], acc[mi][n][r]);
            }
        }
    }
}

// -------------------------------------------------- pv epilogue: rinv scale + bias + store
__global__ __launch_bounds__(256) void pv_epi(
        const float* __restrict__ acc32, const float* __restrict__ rinv,
        const void* __restrict__ braw, const ushort* __restrict__ hraw,
        void* __restrict__ outraw) {
    int mode = detect_mode(hraw);
    int idx4 = blockIdx.x * 256 + threadIdx.x;          // 0 .. 1048575
    int h = idx4 >> 17;
    int i = (idx4 >> 5) & 4095;
    int og = idx4 & 31;
    float4 v = reinterpret_cast<const float4*>(acc32)[idx4];
    float r = rinv[h * N + i];
    float4 bv;
    if (mode) bv = reinterpret_cast<const float4*>(braw)[og];
    else {
        const ushort* bu = (const ushort*)braw;
        bv.x = b2f(bu[og*4]); bv.y = b2f(bu[og*4+1]); bv.z = b2f(bu[og*4+2]); bv.w = b2f(bu[og*4+3]);
    }
    v.x = v.x * r + bv.x; v.y = v.y * r + bv.y; v.z = v.z * r + bv.z; v.w = v.w * r + bv.w;
    size_t ob = (size_t)i * (NH * FOUT) + h * FOUT + og * 4;
    if (mode) *reinterpret_cast<float4*>((float*)outraw + ob) = v;
    else {
        ushort4 pk; pk.x = f2b(v.x); pk.y = f2b(v.y); pk.z = f2b(v.z); pk.w = f2b(v.w);
        *reinterpret_cast<ushort4*>((ushort*)outraw + ob) = pk;
    }
}

// -------------------------------------------------- weight = sum_h attn
__global__ __launch_bounds__(256) void weight_kernel(const float* __restrict__ es1, const float* __restrict__ es2,
                                                     const float* __restrict__ ed1, const float* __restrict__ ed2,
                                                     const float* __restrict__ rinv,
                                                     const uint* __restrict__ bitsT,
                                                     const ushort* __restrict__ hraw,
                                                     void* __restrict__ outraw) {
    int mode = detect_mode(hraw);
    ushort* woutU = (ushort*)outraw + (size_t)N * (NH * FOUT);
    float*  woutF = (float*)outraw  + (size_t)N * (NH * FOUT);
    int t = threadIdx.x;
    int i0 = blockIdx.x * 16;
    int j0 = blockIdx.y * 1024;
    for (int ji = 0; ji < 4; ++ji) {
        int j = j0 + ji * 256 + t;
        float d1[NH], d2[NH];
#pragma unroll
        for (int hh = 0; hh < NH; ++hh) {
            d1[hh] = ed1[hh * N + j];
            d2[hh] = ed2[hh * N + j];
        }
        int wrow = j >> 5;
        int jb = j & 31;
        for (int i = i0; i < i0 + 16; ++i) {
            uint word = bitsT[(size_t)wrow * N + i];
            float sum = 0.f;
#pragma unroll
            for (int hh = 0; hh < NH; ++hh) {
                float s1 = es1[hh * N + i];
                float s2 = es2[hh * N + i];
                float r  = rinv[hh * N + i];
                float t1 = s1 * d1[hh];
                float e = (t1 >= 1.0f) ? t1 : s2 * d2[hh];
                sum += e * r;
            }
            sum = ((word >> jb) & 1u) ? sum : 0.f;
            size_t oidx = (size_t)i * N + j;
            if (mode == 0) woutU[oidx] = f2b(sum);
            else           woutF[oidx] = sum;
        }
    }
}

// -------------------------------------------------- launch
extern "C" void kernel_launch(void* const* d_in, const int* in_sizes, int n_in,
                              void* d_out, int out_size, void* d_ws, size_t ws_size,
                              hipStream_t stream) {
    (void)in_sizes; (void)n_in; (void)out_size;
    const void* hraw  = d_in[0];                 // [4096][1024]  fp32 (or bf16)
    const int*  adj   = (const int*)d_in[1];     // [4096][4096]  int32
    const void* wraw  = d_in[2];                 // [8][1024][128]
    const void* braw  = d_in[3];                 // [128]
    const void* asraw = d_in[4];                 // [8][128]
    const void* adraw = d_in[5];                 // [8][128]

    char* ws = (char*)d_ws;
    float* lsum = (float*)(ws + 0);              // 128 KiB
    float* rinv = (float*)(ws + 131072);         // 128 KiB
    float* es1  = (float*)(ws + 262144);
    float* es2  = (float*)(ws + 393216);
    float* ed1  = (float*)(ws + 524288);
    float* ed2  = (float*)(ws + 655360);
    uint*  bitsT= (uint*)(ws + 786432);          // 2 MiB -> small end 2883584

    // big scratch: ws if it fits, else d_out tail (weight region, written last)
    float*  acc32; ushort* hpT; ushort* wT;
    const size_t SMALL_END = 2883584;
    if (ws_size >= SMALL_END + 27262976ull) {
        char* b = ws + SMALL_END;
        acc32 = (float*)b;                       // 16 MiB
        hpT   = (ushort*)(b + 16777216);         // 8 MiB
        wT    = (ushort*)(b + 25165824);         // 2 MiB
    } else {
        char* ob = (char*)d_out;
        acc32 = (float*)(ob + 16777216);
        hpT   = (ushort*)(ob + 33554432);
        wT    = (ushort*)(ob + 41943040);
    }

    transpose_w<<<dim3(16, 2, 8), 256, 0, stream>>>(wraw, (const ushort*)hraw, wT);
    pack_adj<<<65536, 256, 0, stream>>>(adj, bitsT);
    zero2<<<4128, 256, 0, stream>>>(acc32, lsum);
    gemm_hp<<<dim3(8, 32), 256, 0, stream>>>(hraw, wT, asraw, adraw, hpT, es1, es2, ed1, ed2);
    rowsum<<<dim3(16, 4, 8), 256, 0, stream>>>(es1, es2, ed1, ed2, bitsT, lsum);
    recip<<<128, 256, 0, stream>>>(lsum, rinv);
    pv_kernel<<<dim3(32, 8, 4), 256, 0, stream>>>(hpT, es1, es2, ed1, ed2, bitsT, acc32);
    pv_epi<<<4096, 256, 0, stream>>>(acc32, rinv, braw, (const ushort*)hraw, d_out);
    weight_kernel<<<dim3(256, 4), 256, 0, stream>>>(es1, es2, ed1, ed2, rinv, bitsT,
                                                    (const ushort*)hraw, d_out);
}

// Round 5
// 545.626 us; speedup vs baseline: 1.0435x; 1.0435x over previous
//
#include <hip/hip_runtime.h>
#include <hip/hip_bf16.h>

// MultiHeadGraphAttention: n=4096, n_head=8, f_in=1024, f_out=128
// score = s_i + d_j (rank-1); exp(leakyrelu(x)) = max(e^s e^d, e^{.2s} e^{.2d})
// softmax normalization commutes with P@V -> accumulate unnormalized, scale in epilogue.
// lsum fused into pv (f32 row sums + quad shuffle). Dtype self-detected (fp32 here).

#define N 4096
#define NH 8
#define FIN 1024
#define FOUT 128
#define LSTR 72   // BK=64 + 8 pad

typedef short bf16x8 __attribute__((ext_vector_type(8)));
typedef float f32x4 __attribute__((ext_vector_type(4)));
typedef unsigned int uint;
typedef unsigned short ushort;

__device__ __forceinline__ float b2f(ushort u){ return __uint_as_float(((uint)u)<<16); }
__device__ __forceinline__ ushort f2b(float f){ uint u=__float_as_uint(f); u=(u+0x7fffu+((u>>16)&1u))>>16; return (ushort)u; }
__device__ __forceinline__ uint pk2cvt(float a, float b){
    float2 f; f.x=a; f.y=b;
    __hip_bfloat162 h = __float22bfloat162_rn(f);   // v_cvt_pk_bf16_f32 on gfx950
    uint r; __builtin_memcpy(&r, &h, 4); return r;
}
__device__ __forceinline__ float sane(float x, float lim){ return fminf(fmaxf(x,-lim),lim); }
// mode 0 = float tensors are bf16; mode 1 = fp32 (even ushorts of fp32 are mantissa noise)
__device__ __forceinline__ int detect_mode(const ushort* hraw){
    ushort u = hraw[2*(threadIdx.x & 63)];
    int e = (u>>7)&0xFF;
    unsigned long long m = __ballot(e>=90 && e<=141);
    return (__popcll(m)>=40)?0:1;
}

// -------------------------------------------------- pack adj into transposed bitmask
__global__ __launch_bounds__(256) void pack_adj(const int* __restrict__ adj,
                                                uint* __restrict__ bitsT) {
    size_t idx = (size_t)blockIdx.x * 256 + threadIdx.x;
    int v = adj[idx];
    unsigned long long m = __ballot(v != 0);
    int lane = threadIdx.x & 63;
    uint i  = (uint)(idx >> 12);
    uint jw = ((uint)idx & 4095u) >> 5;
    if (lane == 0)       bitsT[jw * N + i] = (uint)m;
    else if (lane == 32) bitsT[jw * N + i] = (uint)(m >> 32);
}

// -------------------------------------------------- w -> wT[h][o][f] (bf16)
__global__ __launch_bounds__(256) void transpose_w(const void* __restrict__ wraw,
                                                   const ushort* __restrict__ hraw,
                                                   ushort* __restrict__ wT) {
    __shared__ ushort tile[64][72];
    int mode = detect_mode(hraw);
    int h = blockIdx.z, f0 = blockIdx.x * 64, o0 = blockIdx.y * 64;
    int t = threadIdx.x;
#pragma unroll
    for (int it = 0; it < 2; ++it) {
        int slot = it * 256 + t;
        int row = slot >> 3, c = slot & 7;
        size_t eoff = (size_t)h * (FIN * FOUT) + (size_t)(f0 + row) * FOUT + o0 + c * 8;
        alignas(16) ushort tmp[8];
        if (mode == 0) {
            *reinterpret_cast<uint4*>(tmp) = *reinterpret_cast<const uint4*>((const ushort*)wraw + eoff);
        } else {
            const float* wF = (const float*)wraw;
            float4 x = *reinterpret_cast<const float4*>(wF + eoff);
            float4 y = *reinterpret_cast<const float4*>(wF + eoff + 4);
            uint4 p; p.x = pk2cvt(x.x,x.y); p.y = pk2cvt(x.z,x.w);
            p.z = pk2cvt(y.x,y.y); p.w = pk2cvt(y.z,y.w);
            *reinterpret_cast<uint4*>(tmp) = p;
        }
        *reinterpret_cast<uint4*>(&tile[row][c * 8]) = *reinterpret_cast<uint4*>(tmp);
    }
    __syncthreads();
#pragma unroll
    for (int it = 0; it < 2; ++it) {
        int slot = it * 256 + t;
        int orow = slot >> 3, c = slot & 7;
        alignas(16) ushort tmp[8];
#pragma unroll
        for (int k = 0; k < 8; ++k) tmp[k] = tile[c * 8 + k][orow];
        *reinterpret_cast<uint4*>(wT + (size_t)h * (FIN * FOUT) + (size_t)(o0 + orow) * FIN + f0 + c * 8) =
            *reinterpret_cast<uint4*>(tmp);
    }
}

// -------------------------------------------------- zero acc32 (16 MiB) + lsum (128 KiB)
__global__ __launch_bounds__(256) void zero2(float* __restrict__ acc, float* __restrict__ lsum) {
    int b = blockIdx.x, t = threadIdx.x;
    float4 z; z.x=0.f; z.y=0.f; z.z=0.f; z.w=0.f;
    if (b < 4096) reinterpret_cast<float4*>(acc)[b*256+t] = z;
    else          reinterpret_cast<float4*>(lsum)[(b-4096)*256+t] = z;
}

// -------------------------------------------------- GEMM h' (BK=64) + fused s/d dots + exp tables
__global__ __launch_bounds__(256) void gemm_hp(
        const void* __restrict__ hraw, const ushort* __restrict__ wT,
        const void* __restrict__ asraw, const void* __restrict__ adraw,
        ushort* __restrict__ hpT,
        float* __restrict__ es1, float* __restrict__ es2,
        float* __restrict__ ed1, float* __restrict__ ed2) {
    __shared__ ushort As[128 * LSTR];
    __shared__ ushort Bs[128 * LSTR];
    __shared__ float sred[2][128];
    __shared__ float dred[2][128];
    int mode = detect_mode((const ushort*)hraw);
    int tid = threadIdx.x;
    int head = blockIdx.x;
    int i0 = blockIdx.y * 128;
    const ushort* hU = (const ushort*)hraw;
    const float*  hF = (const float*)hraw;
    const ushort* Bg = wT + (size_t)head * (FIN * FOUT);
    int wave = tid >> 6, lane = tid & 63;
    int wm = wave >> 1, wn = wave & 1, quad = lane >> 4, l16 = lane & 15;

    float asv[4], adv[4];
#pragma unroll
    for (int n = 0; n < 4; ++n) {
        int ai = head * FOUT + wn * 64 + n * 16 + l16;
        asv[n] = mode ? ((const float*)asraw)[ai] : b2f(((const ushort*)asraw)[ai]);
        adv[n] = mode ? ((const float*)adraw)[ai] : b2f(((const ushort*)adraw)[ai]);
    }

    f32x4 acc[4][4] = {};
    for (int k0 = 0; k0 < FIN; k0 += 64) {
        __syncthreads();
#pragma unroll
        for (int it = 0; it < 4; ++it) {
            int slot = it * 256 + tid;
            int row = slot >> 3, c = slot & 7;
            size_t aoff = (size_t)(i0 + row) * FIN + k0 + c * 8;
            uint4 av;
            if (mode == 0) {
                av = *reinterpret_cast<const uint4*>(hU + aoff);
            } else {
                float4 x = *reinterpret_cast<const float4*>(hF + aoff);
                float4 y = *reinterpret_cast<const float4*>(hF + aoff + 4);
                av.x = pk2cvt(x.x, x.y); av.y = pk2cvt(x.z, x.w);
                av.z = pk2cvt(y.x, y.y); av.w = pk2cvt(y.z, y.w);
            }
            *reinterpret_cast<uint4*>(&As[row * LSTR + c * 8]) = av;
            *reinterpret_cast<uint4*>(&Bs[row * LSTR + c * 8]) =
                *reinterpret_cast<const uint4*>(Bg + (size_t)row * FIN + k0 + c * 8);
        }
        __syncthreads();
#pragma unroll
        for (int kk = 0; kk < 64; kk += 32) {
            bf16x8 a[4], b[4];
#pragma unroll
            for (int m = 0; m < 4; ++m)
                a[m] = *reinterpret_cast<const bf16x8*>(&As[(wm * 64 + m * 16 + l16) * LSTR + kk + quad * 8]);
#pragma unroll
            for (int n = 0; n < 4; ++n)
                b[n] = *reinterpret_cast<const bf16x8*>(&Bs[(wn * 64 + n * 16 + l16) * LSTR + kk + quad * 8]);
#pragma unroll
            for (int m = 0; m < 4; ++m)
#pragma unroll
                for (int n = 0; n < 4; ++n)
                    acc[m][n] = __builtin_amdgcn_mfma_f32_16x16x32_bf16(a[m], b[n], acc[m][n], 0, 0, 0);
        }
    }
    // store hpT[h][o][i]
#pragma unroll
    for (int m = 0; m < 4; ++m) {
#pragma unroll
        for (int n = 0; n < 4; ++n) {
            int col = wn * 64 + n * 16 + l16;
            int rbase = i0 + wm * 64 + m * 16 + quad * 4;
            uint2 pk;
            pk.x = pk2cvt(acc[m][n][0], acc[m][n][1]);
            pk.y = pk2cvt(acc[m][n][2], acc[m][n][3]);
            *reinterpret_cast<uint2*>(hpT + (size_t)head * (FOUT * N) + (size_t)col * N + rbase) = pk;
        }
    }
    // fused s,d dot reduction (over o) + exp tables
#pragma unroll
    for (int m = 0; m < 4; ++m) {
#pragma unroll
        for (int r = 0; r < 4; ++r) {
            float s = 0.f, d = 0.f;
#pragma unroll
            for (int n = 0; n < 4; ++n) { s += acc[m][n][r] * asv[n]; d += acc[m][n][r] * adv[n]; }
#pragma unroll
            for (int off = 1; off < 16; off <<= 1) { s += __shfl_xor(s, off); d += __shfl_xor(d, off); }
            if (l16 == 0) {
                int row = wm * 64 + m * 16 + quad * 4 + r;
                sred[wn][row] = s; dred[wn][row] = d;
            }
        }
    }
    __syncthreads();
    if (tid < 128) {
        int i = i0 + tid;
        float s = sane(sred[0][tid] + sred[1][tid], 30.f);
        float d = sane(dred[0][tid] + dred[1][tid], 30.f);
        es1[head * N + i] = __expf(s);       es2[head * N + i] = __expf(0.2f * s);
        ed1[head * N + i] = __expf(d);       ed2[head * N + i] = __expf(0.2f * d);
    }
}

// -------------------------------------------------- pv: unnormalized P @ h' + fused lsum
// Block: 64 i-rows x 128 o, K-half (2048). Wave: 16 i x 128 o (8 n-frags). No LDS, no barriers.
__global__ __launch_bounds__(256) void pv_kernel(
        const ushort* __restrict__ hpT,
        const float* __restrict__ es1, const float* __restrict__ es2,
        const float* __restrict__ ed1, const float* __restrict__ ed2,
        const uint* __restrict__ bitsT,
        float* __restrict__ acc32, float* __restrict__ lsum) {
    int t = threadIdx.x;
    int i0 = blockIdx.x * 64, hh = blockIdx.y, kb = blockIdx.z * 2048;
    int w = t >> 6, lane = t & 63;
    int quad = lane >> 4, l16 = lane & 15;
    int wsh = quad * 8;
    int irow = i0 + w * 16 + l16;
    float s1 = es1[hh * N + irow];
    float s2 = es2[hh * N + irow];
    const ushort* bp[8];
#pragma unroll
    for (int n = 0; n < 8; ++n)
        bp[n] = hpT + ((size_t)hh * FOUT + n * 16 + l16) * N + wsh;
    const float* e1p = ed1 + hh * N + wsh;
    const float* e2p = ed2 + hh * N + wsh;
    const uint* wptr = bitsT + (size_t)(kb >> 5) * N + irow;
    float lacc = 0.f;
    f32x4 acc[8] = {};

    for (int k0 = kb; k0 < kb + 2048; k0 += 32) {
        uint word = *wptr >> wsh;
        wptr += N;
        float4 d1a = *reinterpret_cast<const float4*>(e1p + k0);
        float4 d1b = *reinterpret_cast<const float4*>(e1p + k0 + 4);
        float4 d2a = *reinterpret_cast<const float4*>(e2p + k0);
        float4 d2b = *reinterpret_cast<const float4*>(e2p + k0 + 4);
        float e0 = fmaxf(s1*d1a.x, s2*d2a.x); e0 = (word & 1u)   ? e0 : 0.f;
        float e1 = fmaxf(s1*d1a.y, s2*d2a.y); e1 = (word & 2u)   ? e1 : 0.f;
        float e2 = fmaxf(s1*d1a.z, s2*d2a.z); e2 = (word & 4u)   ? e2 : 0.f;
        float e3 = fmaxf(s1*d1a.w, s2*d2a.w); e3 = (word & 8u)   ? e3 : 0.f;
        float e4 = fmaxf(s1*d1b.x, s2*d2b.x); e4 = (word & 16u)  ? e4 : 0.f;
        float e5 = fmaxf(s1*d1b.y, s2*d2b.y); e5 = (word & 32u)  ? e5 : 0.f;
        float e6 = fmaxf(s1*d1b.z, s2*d2b.z); e6 = (word & 64u)  ? e6 : 0.f;
        float e7 = fmaxf(s1*d1b.w, s2*d2b.w); e7 = (word & 128u) ? e7 : 0.f;
        lacc += ((e0 + e1) + (e2 + e3)) + ((e4 + e5) + (e6 + e7));
        uint4 av; av.x = pk2cvt(e0, e1); av.y = pk2cvt(e2, e3);
        av.z = pk2cvt(e4, e5); av.w = pk2cvt(e6, e7);
        bf16x8 a = *reinterpret_cast<bf16x8*>(&av);
#pragma unroll
        for (int n = 0; n < 8; ++n) {
            bf16x8 b = *reinterpret_cast<const bf16x8*>(bp[n] + k0);
            acc[n] = __builtin_amdgcn_mfma_f32_16x16x32_bf16(a, b, acc[n], 0, 0, 0);
        }
    }
    // fused row-sum: reduce over quads (k), lanes<16 hold row totals
    lacc += __shfl_xor(lacc, 16);
    lacc += __shfl_xor(lacc, 32);
    if (lane < 16) atomicAdd(&lsum[hh * N + irow], lacc);
    // output atomics (K-split 2)
    float* arow = acc32 + ((size_t)hh * N + i0 + w * 16 + quad * 4) * FOUT + l16;
#pragma unroll
    for (int n = 0; n < 8; ++n)
#pragma unroll
        for (int r = 0; r < 4; ++r)
            atomicAdd(&arow[(size_t)r * FOUT + n * 16], acc[n][r]);
}

// -------------------------------------------------- recip + pre-scaled tables for weight
__global__ __launch_bounds__(256) void recip2(const float* __restrict__ lsum,
                                              const float* __restrict__ es1, const float* __restrict__ es2,
                                              float* __restrict__ rinv,
                                              float* __restrict__ s1r, float* __restrict__ s2r) {
    int idx = blockIdx.x * 256 + threadIdx.x;
    float v = lsum[idx];
    float r = (v > 1e-30f) ? 1.0f / v : 0.f;
    rinv[idx] = r;
    s1r[idx] = es1[idx] * r;
    s2r[idx] = es2[idx] * r;
}

// -------------------------------------------------- pv epilogue: rinv scale + bias + store
__global__ __launch_bounds__(256) void pv_epi(
        const float* __restrict__ acc32, const float* __restrict__ rinv,
        const void* __restrict__ braw, const ushort* __restrict__ hraw,
        void* __restrict__ outraw) {
    int mode = detect_mode(hraw);
    int idx4 = blockIdx.x * 256 + threadIdx.x;          // 0 .. 1048575
    int h = idx4 >> 17;
    int i = (idx4 >> 5) & 4095;
    int og = idx4 & 31;
    float4 v = reinterpret_cast<const float4*>(acc32)[idx4];
    float r = rinv[h * N + i];
    float4 bv;
    if (mode) bv = reinterpret_cast<const float4*>(braw)[og];
    else {
        const ushort* bu = (const ushort*)braw;
        bv.x = b2f(bu[og*4]); bv.y = b2f(bu[og*4+1]); bv.z = b2f(bu[og*4+2]); bv.w = b2f(bu[og*4+3]);
    }
    v.x = v.x * r + bv.x; v.y = v.y * r + bv.y; v.z = v.z * r + bv.z; v.w = v.w * r + bv.w;
    size_t ob = (size_t)i * (NH * FOUT) + h * FOUT + og * 4;
    if (mode) *reinterpret_cast<float4*>((float*)outraw + ob) = v;
    else {
        uint2 pk; pk.x = pk2cvt(v.x, v.y); pk.y = pk2cvt(v.z, v.w);
        *reinterpret_cast<uint2*>((ushort*)outraw + ob) = pk;
    }
}

// -------------------------------------------------- weight = sum_h attn (pre-scaled tables)
__global__ __launch_bounds__(256) void weight_kernel(
        const float* __restrict__ s1r, const float* __restrict__ s2r,
        const float* __restrict__ ed1, const float* __restrict__ ed2,
        const uint* __restrict__ bitsT,
        const ushort* __restrict__ hraw,
        void* __restrict__ outraw) {
    int mode = detect_mode(hraw);
    ushort* woutU = (ushort*)outraw + (size_t)N * (NH * FOUT);
    float*  woutF = (float*)outraw  + (size_t)N * (NH * FOUT);
    int t = threadIdx.x;
    int j = blockIdx.x * 512 + t * 2;
    int i0 = blockIdx.y * 32;
    float2 d1[NH], d2[NH];
#pragma unroll
    for (int hh = 0; hh < NH; ++hh) {
        d1[hh] = *reinterpret_cast<const float2*>(ed1 + hh * N + j);
        d2[hh] = *reinterpret_cast<const float2*>(ed2 + hh * N + j);
    }
    int wrow = j >> 5;
    int jsh = j & 31;
    for (int i = i0; i < i0 + 32; ++i) {
        uint word = (bitsT[(size_t)wrow * N + i] >> jsh) & 3u;
        float sum0 = 0.f, sum1 = 0.f;
#pragma unroll
        for (int hh = 0; hh < NH; ++hh) {
            float a = s1r[hh * N + i];   // uniform over block -> s_load
            float b = s2r[hh * N + i];
            sum0 += fmaxf(a * d1[hh].x, b * d2[hh].x);
            sum1 += fmaxf(a * d1[hh].y, b * d2[hh].y);
        }
        sum0 = (word & 1u) ? sum0 : 0.f;
        sum1 = (word & 2u) ? sum1 : 0.f;
        size_t oidx = (size_t)i * N + j;
        if (mode) {
            float2 st; st.x = sum0; st.y = sum1;
            *reinterpret_cast<float2*>(woutF + oidx) = st;
        } else {
            *reinterpret_cast<uint*>(woutU + oidx) = pk2cvt(sum0, sum1);
        }
    }
}

// -------------------------------------------------- launch
extern "C" void kernel_launch(void* const* d_in, const int* in_sizes, int n_in,
                              void* d_out, int out_size, void* d_ws, size_t ws_size,
                              hipStream_t stream) {
    (void)in_sizes; (void)n_in; (void)out_size;
    const void* hraw  = d_in[0];                 // [4096][1024]  fp32 (or bf16)
    const int*  adj   = (const int*)d_in[1];     // [4096][4096]  int32
    const void* wraw  = d_in[2];                 // [8][1024][128]
    const void* braw  = d_in[3];                 // [128]
    const void* asraw = d_in[4];                 // [8][128]
    const void* adraw = d_in[5];                 // [8][128]

    char* ws = (char*)d_ws;
    float* lsum = (float*)(ws + 0);
    float* rinv = (float*)(ws + 131072);
    float* es1  = (float*)(ws + 262144);
    float* es2  = (float*)(ws + 393216);
    float* ed1  = (float*)(ws + 524288);
    float* ed2  = (float*)(ws + 655360);
    float* s1r  = (float*)(ws + 786432);
    float* s2r  = (float*)(ws + 917504);
    uint*  bitsT= (uint*)(ws + 1048576);         // 2 MiB
    ushort* wT  = (ushort*)(ws + 3145728);       // 2 MiB -> small end 5242880

    // big scratch: ws if it fits, else d_out tail (weight region, written last)
    float*  acc32; ushort* hpT;
    const size_t SMALL_END = 5242880;
    if (ws_size >= SMALL_END + 25165824ull) {
        char* b = ws + SMALL_END;
        acc32 = (float*)b;                       // 16 MiB
        hpT   = (ushort*)(b + 16777216);         // 8 MiB
    } else {
        char* ob = (char*)d_out;
        acc32 = (float*)(ob + 16777216);         // [16,32) MiB
        hpT   = (ushort*)(ob + 33554432);        // [32,40) MiB
    }

    transpose_w<<<dim3(16, 2, 8), 256, 0, stream>>>(wraw, (const ushort*)hraw, wT);
    pack_adj<<<65536, 256, 0, stream>>>(adj, bitsT);
    zero2<<<4128, 256, 0, stream>>>(acc32, lsum);
    gemm_hp<<<dim3(8, 32), 256, 0, stream>>>(hraw, wT, asraw, adraw, hpT, es1, es2, ed1, ed2);
    pv_kernel<<<dim3(64, 8, 2), 256, 0, stream>>>(hpT, es1, es2, ed1, ed2, bitsT, acc32, lsum);
    recip2<<<128, 256, 0, stream>>>(lsum, es1, es2, rinv, s1r, s2r);
    pv_epi<<<4096, 256, 0, stream>>>(acc32, rinv, braw, (const ushort*)hraw, d_out);
    weight_kernel<<<dim3(8, 128), 256, 0, stream>>>(s1r, s2r, ed1, ed2, bitsT,
                                                    (const ushort*)hraw, d_out);
}

// Round 6
// 471.810 us; speedup vs baseline: 1.2068x; 1.1565x over previous
//
#include <hip/hip_runtime.h>
#include <hip/hip_bf16.h>

// MultiHeadGraphAttention: n=4096, n_head=8, f_in=1024, f_out=128
// score = s_i + d_j (rank-1); exp(leakyrelu(x)) = max(e^s e^d, e^{.2s} e^{.2d})
// pv: full-K per block -> self-normalizing (rowsum via MFMA ones-column), no atomics.
// Dtype self-detected (fp32 on this harness; bf16 path kept).

#define N 4096
#define NH 8
#define FIN 1024
#define FOUT 128
#define BSTR 72   // 64 + 8 pad (shorts) -> balanced banks for ds_read_b128

typedef short bf16x8 __attribute__((ext_vector_type(8)));
typedef float f32x4 __attribute__((ext_vector_type(4)));
typedef unsigned int uint;
typedef unsigned short ushort;

__device__ __forceinline__ float b2f(ushort u){ return __uint_as_float(((uint)u)<<16); }
__device__ __forceinline__ ushort f2b(float f){ uint u=__float_as_uint(f); u=(u+0x7fffu+((u>>16)&1u))>>16; return (ushort)u; }
__device__ __forceinline__ uint pk2cvt(float a, float b){
    float2 f; f.x=a; f.y=b;
    __hip_bfloat162 h = __float22bfloat162_rn(f);   // v_cvt_pk_bf16_f32
    uint r; __builtin_memcpy(&r, &h, 4); return r;
}
__device__ __forceinline__ float sane(float x, float lim){ return fminf(fmaxf(x,-lim),lim); }
// mode 0 = float tensors are bf16; mode 1 = fp32
__device__ __forceinline__ int detect_mode(const ushort* hraw){
    ushort u = hraw[2*(threadIdx.x & 63)];
    int e = (u>>7)&0xFF;
    unsigned long long m = __ballot(e>=90 && e<=141);
    return (__popcll(m)>=40)?0:1;
}

// -------------------------------------------------- pack adj into transposed bitmask
__global__ __launch_bounds__(256) void pack_adj(const int* __restrict__ adj,
                                                uint* __restrict__ bitsT) {
    size_t idx = (size_t)blockIdx.x * 256 + threadIdx.x;
    int v = adj[idx];
    unsigned long long m = __ballot(v != 0);
    int lane = threadIdx.x & 63;
    uint i  = (uint)(idx >> 12);
    uint jw = ((uint)idx & 4095u) >> 5;
    if (lane == 0)       bitsT[jw * N + i] = (uint)m;
    else if (lane == 32) bitsT[jw * N + i] = (uint)(m >> 32);
}

// -------------------------------------------------- w -> wT[h][o][f] (bf16)
__global__ __launch_bounds__(256) void transpose_w(const void* __restrict__ wraw,
                                                   const ushort* __restrict__ hraw,
                                                   ushort* __restrict__ wT) {
    __shared__ ushort tile[64][72];
    int mode = detect_mode(hraw);
    int h = blockIdx.z, f0 = blockIdx.x * 64, o0 = blockIdx.y * 64;
    int t = threadIdx.x;
#pragma unroll
    for (int it = 0; it < 2; ++it) {
        int slot = it * 256 + t;
        int row = slot >> 3, c = slot & 7;
        size_t eoff = (size_t)h * (FIN * FOUT) + (size_t)(f0 + row) * FOUT + o0 + c * 8;
        alignas(16) ushort tmp[8];
        if (mode == 0) {
            *reinterpret_cast<uint4*>(tmp) = *reinterpret_cast<const uint4*>((const ushort*)wraw + eoff);
        } else {
            const float* wF = (const float*)wraw;
            float4 x = *reinterpret_cast<const float4*>(wF + eoff);
            float4 y = *reinterpret_cast<const float4*>(wF + eoff + 4);
            uint4 p; p.x = pk2cvt(x.x,x.y); p.y = pk2cvt(x.z,x.w);
            p.z = pk2cvt(y.x,y.y); p.w = pk2cvt(y.z,y.w);
            *reinterpret_cast<uint4*>(tmp) = p;
        }
        *reinterpret_cast<uint4*>(&tile[row][c * 8]) = *reinterpret_cast<uint4*>(tmp);
    }
    __syncthreads();
#pragma unroll
    for (int it = 0; it < 2; ++it) {
        int slot = it * 256 + t;
        int orow = slot >> 3, c = slot & 7;
        alignas(16) ushort tmp[8];
#pragma unroll
        for (int k = 0; k < 8; ++k) tmp[k] = tile[c * 8 + k][orow];
        *reinterpret_cast<uint4*>(wT + (size_t)h * (FIN * FOUT) + (size_t)(o0 + orow) * FIN + f0 + c * 8) =
            *reinterpret_cast<uint4*>(tmp);
    }
}

// -------------------------------------------------- GEMM h' (64i x 128o, BK=64) + s/d dots + exp
// grid (8 heads, 64 i-blocks) = 512 blocks, 256 thr. Wave: 16 i x 128 o.
// A-frags direct from global (no cross-wave reuse); B staged in LDS (shared x4).
__global__ __launch_bounds__(256) void gemm_hp(
        const void* __restrict__ hraw, const ushort* __restrict__ wT,
        const void* __restrict__ asraw, const void* __restrict__ adraw,
        ushort* __restrict__ hpT,
        float* __restrict__ es1, float* __restrict__ es2,
        float* __restrict__ ed1, float* __restrict__ ed2) {
    __shared__ ushort Bs[FOUT * BSTR];
    __shared__ float sred[64], dred[64];
    int mode = detect_mode((const ushort*)hraw);
    int t = threadIdx.x;
    int head = blockIdx.x, i0 = blockIdx.y * 64;
    int w = t >> 6, lane = t & 63, quad = lane >> 4, l16 = lane & 15, wsh = quad * 8;
    int arow = i0 + w * 16 + l16;
    const ushort* hU = (const ushort*)hraw;
    const float*  hF = (const float*)hraw;
    int srow = t >> 1, shalf = t & 1;
    const ushort* sg = wT + (size_t)head * FOUT * FIN + (size_t)srow * FIN + shalf * 32;
    ushort* sl = &Bs[srow * BSTR + shalf * 32];

    float asv[8], adv[8];
#pragma unroll
    for (int n = 0; n < 8; ++n) {
        int ai = head * FOUT + n * 16 + l16;
        asv[n] = mode ? ((const float*)asraw)[ai] : b2f(((const ushort*)asraw)[ai]);
        adv[n] = mode ? ((const float*)adraw)[ai] : b2f(((const ushort*)adraw)[ai]);
    }

    f32x4 acc[8] = {};
    uint4 pre[4];
#pragma unroll
    for (int s = 0; s < 4; ++s) pre[s] = *reinterpret_cast<const uint4*>(sg + s * 8);

    for (int c = 0; c < 16; ++c) {
        int k0 = c * 64;
        __syncthreads();
#pragma unroll
        for (int s = 0; s < 4; ++s) *reinterpret_cast<uint4*>(sl + s * 8) = pre[s];
        __syncthreads();
        if (c < 15) {
#pragma unroll
            for (int s = 0; s < 4; ++s)
                pre[s] = *reinterpret_cast<const uint4*>(sg + k0 + 64 + s * 8);
        }
#pragma unroll
        for (int kk = 0; kk < 64; kk += 32) {
            int kg = k0 + kk;
            bf16x8 a;
            if (mode == 0) {
                a = *reinterpret_cast<const bf16x8*>(hU + (size_t)arow * FIN + kg + wsh);
            } else {
                float4 x = *reinterpret_cast<const float4*>(hF + (size_t)arow * FIN + kg + wsh);
                float4 y = *reinterpret_cast<const float4*>(hF + (size_t)arow * FIN + kg + wsh + 4);
                uint4 av; av.x = pk2cvt(x.x,x.y); av.y = pk2cvt(x.z,x.w);
                av.z = pk2cvt(y.x,y.y); av.w = pk2cvt(y.z,y.w);
                a = *reinterpret_cast<bf16x8*>(&av);
            }
#pragma unroll
            for (int n = 0; n < 8; ++n) {
                bf16x8 b = *reinterpret_cast<const bf16x8*>(&Bs[(n * 16 + l16) * BSTR + kk + wsh]);
                acc[n] = __builtin_amdgcn_mfma_f32_16x16x32_bf16(a, b, acc[n], 0, 0, 0);
            }
        }
    }
    // store hpT[h][o][i]  (C: row=quad*4+rr -> i, col=n*16+l16 -> o)
#pragma unroll
    for (int n = 0; n < 8; ++n) {
        uint2 pk;
        pk.x = pk2cvt(acc[n][0], acc[n][1]);
        pk.y = pk2cvt(acc[n][2], acc[n][3]);
        *reinterpret_cast<uint2*>(hpT + ((size_t)head * FOUT + n * 16 + l16) * N + i0 + w * 16 + quad * 4) = pk;
    }
    // s,d dots over o (reduce over l16) + exp tables
#pragma unroll
    for (int rr = 0; rr < 4; ++rr) {
        float s = 0.f, d = 0.f;
#pragma unroll
        for (int n = 0; n < 8; ++n) { s += acc[n][rr] * asv[n]; d += acc[n][rr] * adv[n]; }
#pragma unroll
        for (int off = 1; off < 16; off <<= 1) { s += __shfl_xor(s, off); d += __shfl_xor(d, off); }
        if (l16 == 0) { sred[w * 16 + quad * 4 + rr] = s; dred[w * 16 + quad * 4 + rr] = d; }
    }
    __syncthreads();
    if (t < 64) {
        int i = i0 + t;
        float s = sane(sred[t], 30.f);
        float d = sane(dred[t], 30.f);
        es1[head * N + i] = __expf(s);       es2[head * N + i] = __expf(0.2f * s);
        ed1[head * N + i] = __expf(d);       ed2[head * N + i] = __expf(0.2f * d);
    }
}

// -------------------------------------------------- pv: P @ h', full K, self-normalized
// grid (8 heads, 64 i-blocks) = 512 blocks. Block: 64 i x 128 o x K=4096.
// B (hpT slice) staged in LDS per BK=64 chunk, shared by 4 waves. Row sums via MFMA
// ones-column -> rinv computed in-block; bias fused; direct store. No atomics.
__global__ __launch_bounds__(256) void pv_kernel(
        const ushort* __restrict__ hpT,
        const float* __restrict__ es1, const float* __restrict__ es2,
        const float* __restrict__ ed1, const float* __restrict__ ed2,
        const uint* __restrict__ bitsT,
        const void* __restrict__ braw, const ushort* __restrict__ hraw,
        float* __restrict__ rinv, void* __restrict__ outraw) {
    __shared__ ushort Bs[FOUT * BSTR];
    int mode = detect_mode(hraw);
    int t = threadIdx.x;
    int hh = blockIdx.x, i0 = blockIdx.y * 64;
    int w = t >> 6, lane = t & 63, quad = lane >> 4, l16 = lane & 15, wsh = quad * 8;
    int irow = i0 + w * 16 + l16;
    float s1 = es1[hh * N + irow];
    float s2 = es2[hh * N + irow];
    float bv[8];
#pragma unroll
    for (int n = 0; n < 8; ++n) {
        int o = n * 16 + l16;
        bv[n] = mode ? ((const float*)braw)[o] : b2f(((const ushort*)braw)[o]);
    }
    const ushort* Bg = hpT + (size_t)hh * FOUT * N;
    int srow = t >> 1, shalf = t & 1;
    const ushort* sg = Bg + (size_t)srow * N + shalf * 32;
    ushort* sl = &Bs[srow * BSTR + shalf * 32];
    const float* e1p = ed1 + hh * N + wsh;
    const float* e2p = ed2 + hh * N + wsh;
    const uint* wp = bitsT + irow;
    bf16x8 ones;
#pragma unroll
    for (int j = 0; j < 8; ++j) ones[j] = (short)0x3F80;   // bf16 1.0

    f32x4 acc[8] = {};
    f32x4 accl = {};
    uint4 pre[4];
#pragma unroll
    for (int s = 0; s < 4; ++s) pre[s] = *reinterpret_cast<const uint4*>(sg + s * 8);

    for (int c = 0; c < 64; ++c) {
        int k0 = c * 64;
        __syncthreads();
#pragma unroll
        for (int s = 0; s < 4; ++s) *reinterpret_cast<uint4*>(sl + s * 8) = pre[s];
        __syncthreads();
        if (c < 63) {
#pragma unroll
            for (int s = 0; s < 4; ++s)
                pre[s] = *reinterpret_cast<const uint4*>(sg + k0 + 64 + s * 8);
        }
#pragma unroll
        for (int kk = 0; kk < 64; kk += 32) {
            int kg = k0 + kk;
            uint word = wp[(size_t)(kg >> 5) * N] >> wsh;
            float4 d1a = *reinterpret_cast<const float4*>(e1p + kg);
            float4 d1b = *reinterpret_cast<const float4*>(e1p + kg + 4);
            float4 d2a = *reinterpret_cast<const float4*>(e2p + kg);
            float4 d2b = *reinterpret_cast<const float4*>(e2p + kg + 4);
            float e0 = fmaxf(s1*d1a.x, s2*d2a.x); e0 = (word & 1u)   ? e0 : 0.f;
            float e1 = fmaxf(s1*d1a.y, s2*d2a.y); e1 = (word & 2u)   ? e1 : 0.f;
            float e2 = fmaxf(s1*d1a.z, s2*d2a.z); e2 = (word & 4u)   ? e2 : 0.f;
            float e3 = fmaxf(s1*d1a.w, s2*d2a.w); e3 = (word & 8u)   ? e3 : 0.f;
            float e4 = fmaxf(s1*d1b.x, s2*d2b.x); e4 = (word & 16u)  ? e4 : 0.f;
            float e5 = fmaxf(s1*d1b.y, s2*d2b.y); e5 = (word & 32u)  ? e5 : 0.f;
            float e6 = fmaxf(s1*d1b.z, s2*d2b.z); e6 = (word & 64u)  ? e6 : 0.f;
            float e7 = fmaxf(s1*d1b.w, s2*d2b.w); e7 = (word & 128u) ? e7 : 0.f;
            uint4 av; av.x = pk2cvt(e0, e1); av.y = pk2cvt(e2, e3);
            av.z = pk2cvt(e4, e5); av.w = pk2cvt(e6, e7);
            bf16x8 a = *reinterpret_cast<bf16x8*>(&av);
            accl = __builtin_amdgcn_mfma_f32_16x16x32_bf16(a, ones, accl, 0, 0, 0);
#pragma unroll
            for (int n = 0; n < 8; ++n) {
                bf16x8 b = *reinterpret_cast<const bf16x8*>(&Bs[(n * 16 + l16) * BSTR + kk + wsh]);
                acc[n] = __builtin_amdgcn_mfma_f32_16x16x32_bf16(a, b, acc[n], 0, 0, 0);
            }
        }
    }
    // rowsum -> rinv (accl[rr] identical across l16 lanes)
    float r[4];
#pragma unroll
    for (int rr = 0; rr < 4; ++rr)
        r[rr] = (accl[rr] > 1e-30f) ? 1.0f / accl[rr] : 0.f;
    if (l16 == 0) {
#pragma unroll
        for (int rr = 0; rr < 4; ++rr)
            rinv[hh * N + i0 + w * 16 + quad * 4 + rr] = r[rr];
    }
    // normalize + bias + store out[i][hh*128+o]
    float* outF = (float*)outraw;
    ushort* outU = (ushort*)outraw;
#pragma unroll
    for (int n = 0; n < 8; ++n) {
#pragma unroll
        for (int rr = 0; rr < 4; ++rr) {
            int row = i0 + w * 16 + quad * 4 + rr;
            float val = acc[n][rr] * r[rr] + bv[n];
            size_t oidx = (size_t)row * (NH * FOUT) + hh * FOUT + n * 16 + l16;
            if (mode) outF[oidx] = val;
            else      outU[oidx] = f2b(val);
        }
    }
}

// -------------------------------------------------- pre-scaled tables for weight
__global__ __launch_bounds__(256) void scale2(const float* __restrict__ rinv,
                                              const float* __restrict__ es1, const float* __restrict__ es2,
                                              float* __restrict__ s1r, float* __restrict__ s2r) {
    int idx = blockIdx.x * 256 + threadIdx.x;
    float r = rinv[idx];
    s1r[idx] = es1[idx] * r;
    s2r[idx] = es2[idx] * r;
}

// -------------------------------------------------- weight = sum_h attn
__global__ __launch_bounds__(256) void weight_kernel(
        const float* __restrict__ s1r, const float* __restrict__ s2r,
        const float* __restrict__ ed1, const float* __restrict__ ed2,
        const uint* __restrict__ bitsT,
        const ushort* __restrict__ hraw,
        void* __restrict__ outraw) {
    int mode = detect_mode(hraw);
    ushort* woutU = (ushort*)outraw + (size_t)N * (NH * FOUT);
    float*  woutF = (float*)outraw  + (size_t)N * (NH * FOUT);
    int t = threadIdx.x;
    int j = blockIdx.x * 1024 + t * 4;
    int i0 = blockIdx.y * 32;
    float4 d1[NH], d2[NH];
#pragma unroll
    for (int hh = 0; hh < NH; ++hh) {
        d1[hh] = *reinterpret_cast<const float4*>(ed1 + hh * N + j);
        d2[hh] = *reinterpret_cast<const float4*>(ed2 + hh * N + j);
    }
    int wrow = j >> 5;
    int jsh = j & 31;
    for (int i = i0; i < i0 + 32; ++i) {
        uint wbits = bitsT[(size_t)wrow * N + i] >> jsh;
        float sx = 0.f, sy = 0.f, sz = 0.f, sw = 0.f;
#pragma unroll
        for (int hh = 0; hh < NH; ++hh) {
            float a = s1r[hh * N + i];   // block-uniform -> s_load
            float b = s2r[hh * N + i];
            sx += fmaxf(a * d1[hh].x, b * d2[hh].x);
            sy += fmaxf(a * d1[hh].y, b * d2[hh].y);
            sz += fmaxf(a * d1[hh].z, b * d2[hh].z);
            sw += fmaxf(a * d1[hh].w, b * d2[hh].w);
        }
        sx = (wbits & 1u) ? sx : 0.f;
        sy = (wbits & 2u) ? sy : 0.f;
        sz = (wbits & 4u) ? sz : 0.f;
        sw = (wbits & 8u) ? sw : 0.f;
        size_t oidx = (size_t)i * N + j;
        if (mode) {
            float4 st; st.x = sx; st.y = sy; st.z = sz; st.w = sw;
            *reinterpret_cast<float4*>(woutF + oidx) = st;
        } else {
            uint2 pk; pk.x = pk2cvt(sx, sy); pk.y = pk2cvt(sz, sw);
            *reinterpret_cast<uint2*>(woutU + oidx) = pk;
        }
    }
}

// -------------------------------------------------- launch
extern "C" void kernel_launch(void* const* d_in, const int* in_sizes, int n_in,
                              void* d_out, int out_size, void* d_ws, size_t ws_size,
                              hipStream_t stream) {
    (void)in_sizes; (void)n_in; (void)out_size;
    const void* hraw  = d_in[0];                 // [4096][1024]  fp32 (or bf16)
    const int*  adj   = (const int*)d_in[1];     // [4096][4096]  int32
    const void* wraw  = d_in[2];                 // [8][1024][128]
    const void* braw  = d_in[3];                 // [128]
    const void* asraw = d_in[4];                 // [8][128]
    const void* adraw = d_in[5];                 // [8][128]

    char* ws = (char*)d_ws;
    float* rinv = (float*)(ws + 0);
    float* es1  = (float*)(ws + 131072);
    float* es2  = (float*)(ws + 262144);
    float* ed1  = (float*)(ws + 393216);
    float* ed2  = (float*)(ws + 524288);
    float* s1r  = (float*)(ws + 655360);
    float* s2r  = (float*)(ws + 786432);
    uint*  bitsT= (uint*)(ws + 917504);          // 2 MiB
    ushort* wT  = (ushort*)(ws + 3014656);       // 2 MiB -> small end 5111808

    // hpT (8 MiB): ws if it fits, else d_out tail (weight region; pv reads it
    // before weight_kernel overwrites, and weight_kernel runs last)
    ushort* hpT;
    if (ws_size >= 5111808ull + 8388608ull) hpT = (ushort*)(ws + 5111808);
    else                                    hpT = (ushort*)((char*)d_out + 16777216);

    transpose_w<<<dim3(16, 2, 8), 256, 0, stream>>>(wraw, (const ushort*)hraw, wT);
    pack_adj<<<65536, 256, 0, stream>>>(adj, bitsT);
    gemm_hp<<<dim3(8, 64), 256, 0, stream>>>(hraw, wT, asraw, adraw, hpT, es1, es2, ed1, ed2);
    pv_kernel<<<dim3(8, 64), 256, 0, stream>>>(hpT, es1, es2, ed1, ed2, bitsT,
                                               braw, (const ushort*)hraw, rinv, d_out);
    scale2<<<128, 256, 0, stream>>>(rinv, es1, es2, s1r, s2r);
    weight_kernel<<<dim3(4, 128), 256, 0, stream>>>(s1r, s2r, ed1, ed2, bitsT,
                                                    (const ushort*)hraw, d_out);
}

// Round 7
// 422.723 us; speedup vs baseline: 1.3469x; 1.1161x over previous
//
#include <hip/hip_runtime.h>
#include <hip/hip_bf16.h>

// MultiHeadGraphAttention: n=4096, n_head=8, f_in=1024, f_out=128
// score = s_i + d_j (rank-1); exp(leakyrelu(x)) = max(e^s e^d, e^{.2s} e^{.2d})
// pv: K-split x4, LDS-shared B (XOR-swizzled), 32 i/wave, atomic fp32 accum.
// Dtype self-detected (fp32 on this harness; bf16 path kept).

#define N 4096
#define NH 8
#define FIN 1024
#define FOUT 128

typedef short bf16x8 __attribute__((ext_vector_type(8)));
typedef float f32x4 __attribute__((ext_vector_type(4)));
typedef unsigned int uint;
typedef unsigned short ushort;

__device__ __forceinline__ float b2f(ushort u){ return __uint_as_float(((uint)u)<<16); }
__device__ __forceinline__ ushort f2b(float f){ uint u=__float_as_uint(f); u=(u+0x7fffu+((u>>16)&1u))>>16; return (ushort)u; }
__device__ __forceinline__ uint pk2cvt(float a, float b){
    float2 f; f.x=a; f.y=b;
    __hip_bfloat162 h = __float22bfloat162_rn(f);   // v_cvt_pk_bf16_f32
    uint r; __builtin_memcpy(&r, &h, 4); return r;
}
__device__ __forceinline__ float sane(float x, float lim){ return fminf(fmaxf(x,-lim),lim); }
// XOR-swizzled LDS offset (shorts): row r (0..127), col-group cg (0..7, 8 shorts each).
// Every 16-lane phase of b128 read/write lands 2-way per bank-group = conflict-free.
__device__ __forceinline__ int swz(int r, int cg){ return r*64 + (((cg) ^ (r & 7)) << 3); }
// mode 0 = float tensors are bf16; mode 1 = fp32
__device__ __forceinline__ int detect_mode(const ushort* hraw){
    ushort u = hraw[2*(threadIdx.x & 63)];
    int e = (u>>7)&0xFF;
    unsigned long long m = __ballot(e>=90 && e<=141);
    return (__popcll(m)>=40)?0:1;
}

// -------------------------------------------------- pack adj into transposed bitmask
__global__ __launch_bounds__(256) void pack_adj(const int* __restrict__ adj,
                                                uint* __restrict__ bitsT) {
    size_t idx = (size_t)blockIdx.x * 256 + threadIdx.x;
    int v = adj[idx];
    unsigned long long m = __ballot(v != 0);
    int lane = threadIdx.x & 63;
    uint i  = (uint)(idx >> 12);
    uint jw = ((uint)idx & 4095u) >> 5;
    if (lane == 0)       bitsT[jw * N + i] = (uint)m;
    else if (lane == 32) bitsT[jw * N + i] = (uint)(m >> 32);
}

// -------------------------------------------------- w -> wT[h][o][f] (bf16)
__global__ __launch_bounds__(256) void transpose_w(const void* __restrict__ wraw,
                                                   const ushort* __restrict__ hraw,
                                                   ushort* __restrict__ wT) {
    __shared__ ushort tile[64][72];
    int mode = detect_mode(hraw);
    int h = blockIdx.z, f0 = blockIdx.x * 64, o0 = blockIdx.y * 64;
    int t = threadIdx.x;
#pragma unroll
    for (int it = 0; it < 2; ++it) {
        int slot = it * 256 + t;
        int row = slot >> 3, c = slot & 7;
        size_t eoff = (size_t)h * (FIN * FOUT) + (size_t)(f0 + row) * FOUT + o0 + c * 8;
        alignas(16) ushort tmp[8];
        if (mode == 0) {
            *reinterpret_cast<uint4*>(tmp) = *reinterpret_cast<const uint4*>((const ushort*)wraw + eoff);
        } else {
            const float* wF = (const float*)wraw;
            float4 x = *reinterpret_cast<const float4*>(wF + eoff);
            float4 y = *reinterpret_cast<const float4*>(wF + eoff + 4);
            uint4 p; p.x = pk2cvt(x.x,x.y); p.y = pk2cvt(x.z,x.w);
            p.z = pk2cvt(y.x,y.y); p.w = pk2cvt(y.z,y.w);
            *reinterpret_cast<uint4*>(tmp) = p;
        }
        *reinterpret_cast<uint4*>(&tile[row][c * 8]) = *reinterpret_cast<uint4*>(tmp);
    }
    __syncthreads();
#pragma unroll
    for (int it = 0; it < 2; ++it) {
        int slot = it * 256 + t;
        int orow = slot >> 3, c = slot & 7;
        alignas(16) ushort tmp[8];
#pragma unroll
        for (int k = 0; k < 8; ++k) tmp[k] = tile[c * 8 + k][orow];
        *reinterpret_cast<uint4*>(wT + (size_t)h * (FIN * FOUT) + (size_t)(o0 + orow) * FIN + f0 + c * 8) =
            *reinterpret_cast<uint4*>(tmp);
    }
}

// -------------------------------------------------- zero acc32 (16 MiB) + lsum (128 KiB)
__global__ __launch_bounds__(256) void zero2(float* __restrict__ acc, float* __restrict__ lsum) {
    int b = blockIdx.x, t = threadIdx.x;
    float4 z; z.x=0.f; z.y=0.f; z.z=0.f; z.w=0.f;
    if (b < 4096) reinterpret_cast<float4*>(acc)[b*256+t] = z;
    else          reinterpret_cast<float4*>(lsum)[(b-4096)*256+t] = z;
}

// -------------------------------------------------- GEMM h' (64i x 128o, BK=64) + s/d dots + exp
// grid (64 i-blocks, 8 heads). Wave: 16 i x 128 o. A prefetched from global; B LDS-shared.
__global__ __launch_bounds__(256) void gemm_hp(
        const void* __restrict__ hraw, const ushort* __restrict__ wT,
        const void* __restrict__ asraw, const void* __restrict__ adraw,
        ushort* __restrict__ hpT,
        float* __restrict__ es1, float* __restrict__ es2,
        float* __restrict__ ed1, float* __restrict__ ed2) {
    __shared__ ushort Bs[FOUT * 64];
    __shared__ float sred[64], dred[64];
    int mode = detect_mode((const ushort*)hraw);
    int t = threadIdx.x;
    int i0 = blockIdx.x * 64, head = blockIdx.y;
    int w = t >> 6, lane = t & 63, quad = lane >> 4, l16 = lane & 15, wsh = quad * 8;
    int arow = i0 + w * 16 + l16;
    const ushort* hU = (const ushort*)hraw;
    const float*  hF = (const float*)hraw;
    int srow = t >> 1, shalf = t & 1;
    const ushort* sg = wT + (size_t)head * FOUT * FIN + (size_t)srow * FIN + shalf * 32;

    float asv[8], adv[8];
#pragma unroll
    for (int n = 0; n < 8; ++n) {
        int ai = head * FOUT + n * 16 + l16;
        asv[n] = mode ? ((const float*)asraw)[ai] : b2f(((const ushort*)asraw)[ai]);
        adv[n] = mode ? ((const float*)adraw)[ai] : b2f(((const ushort*)adraw)[ai]);
    }

    f32x4 acc[8] = {};
    uint4 pre[4];
#pragma unroll
    for (int s = 0; s < 4; ++s) pre[s] = *reinterpret_cast<const uint4*>(sg + s * 8);
    // A prefetch chunk 0
    uint4 au[2]; float4 af[2][2];
    if (mode == 0) {
#pragma unroll
        for (int kk = 0; kk < 2; ++kk)
            au[kk] = *reinterpret_cast<const uint4*>(hU + (size_t)arow * FIN + kk * 32 + wsh);
    } else {
#pragma unroll
        for (int kk = 0; kk < 2; ++kk) {
            af[kk][0] = *reinterpret_cast<const float4*>(hF + (size_t)arow * FIN + kk * 32 + wsh);
            af[kk][1] = *reinterpret_cast<const float4*>(hF + (size_t)arow * FIN + kk * 32 + wsh + 4);
        }
    }

    for (int c = 0; c < 16; ++c) {
        int k0 = c * 64;
        __syncthreads();
#pragma unroll
        for (int s = 0; s < 4; ++s)
            *reinterpret_cast<uint4*>(&Bs[swz(srow, shalf * 4 + s)]) = pre[s];
        __syncthreads();
        // materialize current A frags
        bf16x8 a2[2];
        if (mode == 0) {
            a2[0] = *reinterpret_cast<bf16x8*>(&au[0]);
            a2[1] = *reinterpret_cast<bf16x8*>(&au[1]);
        } else {
#pragma unroll
            for (int kk = 0; kk < 2; ++kk) {
                uint4 av; av.x = pk2cvt(af[kk][0].x, af[kk][0].y); av.y = pk2cvt(af[kk][0].z, af[kk][0].w);
                av.z = pk2cvt(af[kk][1].x, af[kk][1].y); av.w = pk2cvt(af[kk][1].z, af[kk][1].w);
                a2[kk] = *reinterpret_cast<bf16x8*>(&av);
            }
        }
        // prefetch next B + A
        if (c < 15) {
#pragma unroll
            for (int s = 0; s < 4; ++s)
                pre[s] = *reinterpret_cast<const uint4*>(sg + k0 + 64 + s * 8);
            if (mode == 0) {
#pragma unroll
                for (int kk = 0; kk < 2; ++kk)
                    au[kk] = *reinterpret_cast<const uint4*>(hU + (size_t)arow * FIN + k0 + 64 + kk * 32 + wsh);
            } else {
#pragma unroll
                for (int kk = 0; kk < 2; ++kk) {
                    af[kk][0] = *reinterpret_cast<const float4*>(hF + (size_t)arow * FIN + k0 + 64 + kk * 32 + wsh);
                    af[kk][1] = *reinterpret_cast<const float4*>(hF + (size_t)arow * FIN + k0 + 64 + kk * 32 + wsh + 4);
                }
            }
        }
#pragma unroll
        for (int kk = 0; kk < 2; ++kk) {
            int cg0 = kk * 4 + quad;
#pragma unroll
            for (int n = 0; n < 8; ++n) {
                bf16x8 b = *reinterpret_cast<const bf16x8*>(&Bs[swz(n * 16 + l16, cg0)]);
                acc[n] = __builtin_amdgcn_mfma_f32_16x16x32_bf16(a2[kk], b, acc[n], 0, 0, 0);
            }
        }
    }
    // store hpT[h][o][i]  (C: row=quad*4+rr -> i, col=n*16+l16 -> o)
#pragma unroll
    for (int n = 0; n < 8; ++n) {
        uint2 pk;
        pk.x = pk2cvt(acc[n][0], acc[n][1]);
        pk.y = pk2cvt(acc[n][2], acc[n][3]);
        *reinterpret_cast<uint2*>(hpT + ((size_t)head * FOUT + n * 16 + l16) * N + i0 + w * 16 + quad * 4) = pk;
    }
    // s,d dots over o (reduce over l16) + exp tables
#pragma unroll
    for (int rr = 0; rr < 4; ++rr) {
        float s = 0.f, d = 0.f;
#pragma unroll
        for (int n = 0; n < 8; ++n) { s += acc[n][rr] * asv[n]; d += acc[n][rr] * adv[n]; }
#pragma unroll
        for (int off = 1; off < 16; off <<= 1) { s += __shfl_xor(s, off); d += __shfl_xor(d, off); }
        if (l16 == 0) { sred[w * 16 + quad * 4 + rr] = s; dred[w * 16 + quad * 4 + rr] = d; }
    }
    __syncthreads();
    if (t < 64) {
        int i = i0 + t;
        float s = sane(sred[t], 30.f);
        float d = sane(dred[t], 30.f);
        es1[head * N + i] = __expf(s);       es2[head * N + i] = __expf(0.2f * s);
        ed1[head * N + i] = __expf(d);       ed2[head * N + i] = __expf(0.2f * d);
    }
}

// -------------------------------------------------- pv: unnormalized P @ h' + fused lsum
// grid (32 i-blocks x 8 heads x 4 ksplit) = 1024 blocks. Block: 128 i x 128 o x 1024 k.
// Wave: 32 i (2 A-frags) x 128 o -> every LDS B-frag feeds 2 MFMAs. Swizzled LDS.
__global__ __launch_bounds__(256) void pv_kernel(
        const ushort* __restrict__ hpT,
        const float* __restrict__ es1, const float* __restrict__ es2,
        const float* __restrict__ ed1, const float* __restrict__ ed2,
        const uint* __restrict__ bitsT,
        float* __restrict__ acc32, float* __restrict__ lsum) {
    __shared__ ushort Bs[FOUT * 64];
    int t = threadIdx.x;
    int i0 = blockIdx.x * 128, hh = blockIdx.y, kb = blockIdx.z * 1024;
    int w = t >> 6, lane = t & 63, quad = lane >> 4, l16 = lane & 15, wsh = quad * 8;
    int irow[2];
    float s1[2], s2[2];
#pragma unroll
    for (int mi = 0; mi < 2; ++mi) {
        irow[mi] = i0 + w * 32 + mi * 16 + l16;
        s1[mi] = es1[hh * N + irow[mi]];
        s2[mi] = es2[hh * N + irow[mi]];
    }
    int srow = t >> 1, shalf = t & 1;
    const ushort* sg = hpT + (size_t)hh * FOUT * N + (size_t)srow * N + kb + shalf * 32;
    const float* e1p = ed1 + hh * N + wsh;
    const float* e2p = ed2 + hh * N + wsh;
    bf16x8 ones;
#pragma unroll
    for (int j = 0; j < 8; ++j) ones[j] = (short)0x3F80;   // bf16 1.0

    f32x4 acc[2][8] = {};
    f32x4 accl[2] = {};
    uint4 pre[4];
#pragma unroll
    for (int s = 0; s < 4; ++s) pre[s] = *reinterpret_cast<const uint4*>(sg + s * 8);

    for (int c = 0; c < 16; ++c) {
        int k0 = kb + c * 64;
        __syncthreads();
#pragma unroll
        for (int s = 0; s < 4; ++s)
            *reinterpret_cast<uint4*>(&Bs[swz(srow, shalf * 4 + s)]) = pre[s];
        __syncthreads();
        if (c < 15) {
#pragma unroll
            for (int s = 0; s < 4; ++s)
                pre[s] = *reinterpret_cast<const uint4*>(sg + (c + 1) * 64 + s * 8);
        }
#pragma unroll
        for (int kk = 0; kk < 2; ++kk) {
            int kg = k0 + kk * 32;
            float4 d1a = *reinterpret_cast<const float4*>(e1p + kg);
            float4 d1b = *reinterpret_cast<const float4*>(e1p + kg + 4);
            float4 d2a = *reinterpret_cast<const float4*>(e2p + kg);
            float4 d2b = *reinterpret_cast<const float4*>(e2p + kg + 4);
            const uint* wrow = bitsT + (size_t)(kg >> 5) * N;
            bf16x8 am[2];
#pragma unroll
            for (int mi = 0; mi < 2; ++mi) {
                uint word = wrow[irow[mi]] >> wsh;
                float e0 = fmaxf(s1[mi]*d1a.x, s2[mi]*d2a.x); e0 = (word & 1u)   ? e0 : 0.f;
                float e1 = fmaxf(s1[mi]*d1a.y, s2[mi]*d2a.y); e1 = (word & 2u)   ? e1 : 0.f;
                float e2 = fmaxf(s1[mi]*d1a.z, s2[mi]*d2a.z); e2 = (word & 4u)   ? e2 : 0.f;
                float e3 = fmaxf(s1[mi]*d1a.w, s2[mi]*d2a.w); e3 = (word & 8u)   ? e3 : 0.f;
                float e4 = fmaxf(s1[mi]*d1b.x, s2[mi]*d2b.x); e4 = (word & 16u)  ? e4 : 0.f;
                float e5 = fmaxf(s1[mi]*d1b.y, s2[mi]*d2b.y); e5 = (word & 32u)  ? e5 : 0.f;
                float e6 = fmaxf(s1[mi]*d1b.z, s2[mi]*d2b.z); e6 = (word & 64u)  ? e6 : 0.f;
                float e7 = fmaxf(s1[mi]*d1b.w, s2[mi]*d2b.w); e7 = (word & 128u) ? e7 : 0.f;
                uint4 av; av.x = pk2cvt(e0, e1); av.y = pk2cvt(e2, e3);
                av.z = pk2cvt(e4, e5); av.w = pk2cvt(e6, e7);
                am[mi] = *reinterpret_cast<bf16x8*>(&av);
                accl[mi] = __builtin_amdgcn_mfma_f32_16x16x32_bf16(am[mi], ones, accl[mi], 0, 0, 0);
            }
            int cg0 = kk * 4 + quad;
#pragma unroll
            for (int n = 0; n < 8; ++n) {
                bf16x8 b = *reinterpret_cast<const bf16x8*>(&Bs[swz(n * 16 + l16, cg0)]);
                acc[0][n] = __builtin_amdgcn_mfma_f32_16x16x32_bf16(am[0], b, acc[0][n], 0, 0, 0);
                acc[1][n] = __builtin_amdgcn_mfma_f32_16x16x32_bf16(am[1], b, acc[1][n], 0, 0, 0);
            }
        }
    }
    // lsum partials (accl[mi][rr] identical across l16 lanes)
    if (l16 == 0) {
#pragma unroll
        for (int mi = 0; mi < 2; ++mi)
#pragma unroll
            for (int rr = 0; rr < 4; ++rr)
                atomicAdd(&lsum[hh * N + i0 + w * 32 + mi * 16 + quad * 4 + rr], accl[mi][rr]);
    }
    // acc32 partials
#pragma unroll
    for (int mi = 0; mi < 2; ++mi) {
        float* arow = acc32 + ((size_t)hh * N + i0 + w * 32 + mi * 16 + quad * 4) * FOUT + l16;
#pragma unroll
        for (int n = 0; n < 8; ++n)
#pragma unroll
            for (int rr = 0; rr < 4; ++rr)
                atomicAdd(&arow[(size_t)rr * FOUT + n * 16], acc[mi][n][rr]);
    }
}

// -------------------------------------------------- recip + pre-scaled tables for weight
__global__ __launch_bounds__(256) void recip2(const float* __restrict__ lsum,
                                              const float* __restrict__ es1, const float* __restrict__ es2,
                                              float* __restrict__ rinv,
                                              float* __restrict__ s1r, float* __restrict__ s2r) {
    int idx = blockIdx.x * 256 + threadIdx.x;
    float v = lsum[idx];
    float r = (v > 1e-30f) ? 1.0f / v : 0.f;
    rinv[idx] = r;
    s1r[idx] = es1[idx] * r;
    s2r[idx] = es2[idx] * r;
}

// -------------------------------------------------- pv epilogue: rinv scale + bias + store
__global__ __launch_bounds__(256) void pv_epi(
        const float* __restrict__ acc32, const float* __restrict__ rinv,
        const void* __restrict__ braw, const ushort* __restrict__ hraw,
        void* __restrict__ outraw) {
    int mode = detect_mode(hraw);
    int idx4 = blockIdx.x * 256 + threadIdx.x;          // 0 .. 1048575
    int h = idx4 >> 17;
    int i = (idx4 >> 5) & 4095;
    int og = idx4 & 31;
    float4 v = reinterpret_cast<const float4*>(acc32)[idx4];
    float r = rinv[h * N + i];
    float4 bv;
    if (mode) bv = reinterpret_cast<const float4*>(braw)[og];
    else {
        const ushort* bu = (const ushort*)braw;
        bv.x = b2f(bu[og*4]); bv.y = b2f(bu[og*4+1]); bv.z = b2f(bu[og*4+2]); bv.w = b2f(bu[og*4+3]);
    }
    v.x = v.x * r + bv.x; v.y = v.y * r + bv.y; v.z = v.z * r + bv.z; v.w = v.w * r + bv.w;
    size_t ob = (size_t)i * (NH * FOUT) + h * FOUT + og * 4;
    if (mode) *reinterpret_cast<float4*>((float*)outraw + ob) = v;
    else {
        uint2 pk; pk.x = pk2cvt(v.x, v.y); pk.y = pk2cvt(v.z, v.w);
        *reinterpret_cast<uint2*>((ushort*)outraw + ob) = pk;
    }
}

// -------------------------------------------------- weight = sum_h attn
__global__ __launch_bounds__(256) void weight_kernel(
        const float* __restrict__ s1r, const float* __restrict__ s2r,
        const float* __restrict__ ed1, const float* __restrict__ ed2,
        const uint* __restrict__ bitsT,
        const ushort* __restrict__ hraw,
        void* __restrict__ outraw) {
    int mode = detect_mode(hraw);
    ushort* woutU = (ushort*)outraw + (size_t)N * (NH * FOUT);
    float*  woutF = (float*)outraw  + (size_t)N * (NH * FOUT);
    int t = threadIdx.x;
    int j = blockIdx.x * 1024 + t * 4;
    int i0 = blockIdx.y * 32;
    float4 d1[NH], d2[NH];
#pragma unroll
    for (int hh = 0; hh < NH; ++hh) {
        d1[hh] = *reinterpret_cast<const float4*>(ed1 + hh * N + j);
        d2[hh] = *reinterpret_cast<const float4*>(ed2 + hh * N + j);
    }
    int wrow = j >> 5;
    int jsh = j & 31;
    for (int i = i0; i < i0 + 32; ++i) {
        uint wbits = bitsT[(size_t)wrow * N + i] >> jsh;
        float sx = 0.f, sy = 0.f, sz = 0.f, sw = 0.f;
#pragma unroll
        for (int hh = 0; hh < NH; ++hh) {
            float a = s1r[hh * N + i];   // block-uniform -> s_load
            float b = s2r[hh * N + i];
            sx += fmaxf(a * d1[hh].x, b * d2[hh].x);
            sy += fmaxf(a * d1[hh].y, b * d2[hh].y);
            sz += fmaxf(a * d1[hh].z, b * d2[hh].z);
            sw += fmaxf(a * d1[hh].w, b * d2[hh].w);
        }
        sx = (wbits & 1u) ? sx : 0.f;
        sy = (wbits & 2u) ? sy : 0.f;
        sz = (wbits & 4u) ? sz : 0.f;
        sw = (wbits & 8u) ? sw : 0.f;
        size_t oidx = (size_t)i * N + j;
        if (mode) {
            float4 st; st.x = sx; st.y = sy; st.z = sz; st.w = sw;
            *reinterpret_cast<float4*>(woutF + oidx) = st;
        } else {
            uint2 pk; pk.x = pk2cvt(sx, sy); pk.y = pk2cvt(sz, sw);
            *reinterpret_cast<uint2*>(woutU + oidx) = pk;
        }
    }
}

// -------------------------------------------------- launch
extern "C" void kernel_launch(void* const* d_in, const int* in_sizes, int n_in,
                              void* d_out, int out_size, void* d_ws, size_t ws_size,
                              hipStream_t stream) {
    (void)in_sizes; (void)n_in; (void)out_size;
    const void* hraw  = d_in[0];                 // [4096][1024]  fp32 (or bf16)
    const int*  adj   = (const int*)d_in[1];     // [4096][4096]  int32
    const void* wraw  = d_in[2];                 // [8][1024][128]
    const void* braw  = d_in[3];                 // [128]
    const void* asraw = d_in[4];                 // [8][128]
    const void* adraw = d_in[5];                 // [8][128]

    char* ws = (char*)d_ws;
    float* lsum = (float*)(ws + 0);
    float* rinv = (float*)(ws + 131072);
    float* es1  = (float*)(ws + 262144);
    float* es2  = (float*)(ws + 393216);
    float* ed1  = (float*)(ws + 524288);
    float* ed2  = (float*)(ws + 655360);
    float* s1r  = (float*)(ws + 786432);
    float* s2r  = (float*)(ws + 917504);
    uint*  bitsT= (uint*)(ws + 1048576);         // 2 MiB
    ushort* wT  = (ushort*)(ws + 3145728);       // 2 MiB -> small end 5242880

    // big scratch: ws if it fits, else d_out tail (weight region, written last)
    float*  acc32; ushort* hpT;
    const size_t SMALL_END = 5242880;
    if (ws_size >= SMALL_END + 25165824ull) {
        char* b = ws + SMALL_END;
        acc32 = (float*)b;                       // 16 MiB
        hpT   = (ushort*)(b + 16777216);         // 8 MiB
    } else {
        char* ob = (char*)d_out;
        acc32 = (float*)(ob + 16777216);         // [16,32) MiB
        hpT   = (ushort*)(ob + 33554432);        // [32,40) MiB
    }

    transpose_w<<<dim3(16, 2, 8), 256, 0, stream>>>(wraw, (const ushort*)hraw, wT);
    pack_adj<<<65536, 256, 0, stream>>>(adj, bitsT);
    zero2<<<4128, 256, 0, stream>>>(acc32, lsum);
    gemm_hp<<<dim3(64, 8), 256, 0, stream>>>(hraw, wT, asraw, adraw, hpT, es1, es2, ed1, ed2);
    pv_kernel<<<dim3(32, 8, 4), 256, 0, stream>>>(hpT, es1, es2, ed1, ed2, bitsT, acc32, lsum);
    recip2<<<128, 256, 0, stream>>>(lsum, es1, es2, rinv, s1r, s2r);
    pv_epi<<<4096, 256, 0, stream>>>(acc32, rinv, braw, (const ushort*)hraw, d_out);
    weight_kernel<<<dim3(4, 128), 256, 0, stream>>>(s1r, s2r, ed1, ed2, bitsT,
                                                    (const ushort*)hraw, d_out);
}